// Round 2
// baseline (145.777 us; speedup 1.0000x reference)
//
#include <hip/hip_runtime.h>
#include <stdint.h>

// ---------------------------------------------------------------------------
// GraphBasedSkipConnection, MI355X. All device buffers are FLOAT32 (reference
// is pure f32). Internally: x converted once to bf16; GEMMs via
// v_mfma_f32_16x16x32_bf16 with f32 accumulation; output written as f32.
//   B=2, H=64, W=64, C=512, C2=256, N = B*H*W = 8192 pixels.
// BN stages folded to per-channel affine y = relu(a*z + c), precomputed.
// ---------------------------------------------------------------------------

typedef __attribute__((ext_vector_type(8))) short bf16x8;
typedef __attribute__((ext_vector_type(4))) float f32x4;

#define EPS_BN 1e-3f

__device__ __forceinline__ short f2bf(float f) {
    union { float f; unsigned u; } cv;
    cv.f = f;
    unsigned r = cv.u + 0x7fffu + ((cv.u >> 16) & 1u);
    return (short)(r >> 16);
}
__device__ __forceinline__ float bf2f(short s) {
    union { unsigned u; float f; } cv;
    cv.u = ((unsigned)(unsigned short)s) << 16;
    return cv.f;
}

// ---- P layout (floats) -----------------------------------------------------
// 0 a1, 1 c1, 2 a4, 3 c4
// 8..264    a2[256]     264..520  c2[256]
// 520..776  a3[256]     776..1032 c3[256]
// 1032..1544 a5[512]    1544..2056 c5[512]
// 2056..2060 w_ea[4]    2060..2064 w_er[4]
// ---------------------------------------------------------------------------

__global__ void prep_params(
    const float* w_ea, const float* b_ea,
    const float* g1, const float* b1, const float* m1, const float* v1,
    const float* b_vu, const float* g2, const float* b2, const float* m2, const float* v2,
    const float* b_eu, const float* g3, const float* b3, const float* m3, const float* v3,
    const float* w_er, const float* b_er,
    const float* g4, const float* b4, const float* m4, const float* v4,
    const float* g5, const float* b5, const float* m5, const float* v5,
    float* P)
{
    int t = threadIdx.x;
    if (t < 512) {
        float a5 = g5[t] * rsqrtf(v5[t] + EPS_BN);
        P[1032 + t] = a5;
        P[1544 + t] = b5[t] - m5[t] * a5;   // w_fc has no bias
    }
    if (t < 256) {
        float a2 = g2[t] * rsqrtf(v2[t] + EPS_BN);
        P[8 + t]   = a2;
        P[264 + t] = (b_vu[t] - m2[t]) * a2 + b2[t];
        float a3 = g3[t] * rsqrtf(v3[t] + EPS_BN);
        P[520 + t] = a3;
        P[776 + t] = (b_eu[t] - m3[t]) * a3 + b3[t];
    }
    if (t < 4) {
        P[2056 + t] = w_ea[t];
        P[2060 + t] = w_er[t];
    }
    if (t == 0) {
        float a1 = g1[0] * rsqrtf(v1[0] + EPS_BN);
        P[0] = a1;
        P[1] = (b_ea[0] - m1[0]) * a1 + b1[0];
        float a4 = g4[0] * rsqrtf(v4[0] + EPS_BN);
        P[2] = a4;
        P[3] = (b_er[0] - m4[0]) * a4 + b4[0];
    }
}

// Pack W[K, Ncol] (row-major f32) into bf16 MFMA B-fragment order:
// tile = nt*(K/32)+kt ; packed[(tile*64+lane)*8+j] = W[kt*32+(lane>>4)*8+j][nt*16+(lane&15)]
__global__ void k_pack(const float* __restrict__ W, short* __restrict__ out, int K, int Ncol) {
    int i = blockIdx.x * 256 + threadIdx.x;
    int lane = i & 63, tile = i >> 6;
    int ktiles = K >> 5;
    int nt = tile / ktiles, kt = tile - nt * ktiles;
    int kbase = (kt << 5) + ((lane >> 4) << 3);
    int col = (nt << 4) + (lane & 15);
    bf16x8 v;
    #pragma unroll
    for (int j = 0; j < 8; ++j) v[j] = f2bf(W[(kbase + j) * Ncol + col]);
    ((bf16x8*)out)[(tile << 6) + lane] = v;
}

// Fused: xb = bf16(x);  agg = relu(a1 * x * (w0*xU + w1*xD + w2*xL + w3*xR) + c1) in bf16
__global__ __launch_bounds__(256) void k_cvt_agg(const float* __restrict__ x,
                                                 const float* __restrict__ P,
                                                 short* __restrict__ xb,
                                                 short* __restrict__ agg)
{
    int idx = blockIdx.x * 256 + threadIdx.x;   // N*C/8 threads
    int n = idx >> 6;
    int ci = idx & 63;                          // channel group of 8
    int bh = n >> 6, h = bh & 63, w = n & 63;
    int bhb = bh & ~63;
    int rowU = ((bhb + ((h + 63) & 63)) << 6) + w;
    int rowD = ((bhb + ((h + 1) & 63)) << 6) + w;
    int rowL = (bh << 6) + ((w + 63) & 63);
    int rowR = (bh << 6) + ((w + 1) & 63);

    const f32x4* xv = (const f32x4*)x;
    int c4 = ci << 1;                           // index in float4 units
    f32x4 vc0 = xv[(n    << 7) + c4], vc1 = xv[(n    << 7) + c4 + 1];
    f32x4 vU0 = xv[(rowU << 7) + c4], vU1 = xv[(rowU << 7) + c4 + 1];
    f32x4 vD0 = xv[(rowD << 7) + c4], vD1 = xv[(rowD << 7) + c4 + 1];
    f32x4 vL0 = xv[(rowL << 7) + c4], vL1 = xv[(rowL << 7) + c4 + 1];
    f32x4 vR0 = xv[(rowR << 7) + c4], vR1 = xv[(rowR << 7) + c4 + 1];

    float w0 = P[2056], w1 = P[2057], w2 = P[2058], w3 = P[2059];
    float a1 = P[0], c1 = P[1];
    bf16x8 ob, xbv;
    #pragma unroll
    for (int j = 0; j < 4; ++j) {
        float xc = vc0[j];
        float S = w0 * vU0[j] + w1 * vD0[j] + w2 * vL0[j] + w3 * vR0[j];
        ob[j] = f2bf(fmaxf(fmaf(a1, xc * S, c1), 0.f));
        xbv[j] = f2bf(xc);
    }
    #pragma unroll
    for (int j = 0; j < 4; ++j) {
        float xc = vc1[j];
        float S = w0 * vU1[j] + w1 * vD1[j] + w2 * vL1[j] + w3 * vR1[j];
        ob[4 + j] = f2bf(fmaxf(fmaf(a1, xc * S, c1), 0.f));
        xbv[4 + j] = f2bf(xc);
    }
    ((bf16x8*)agg)[(n << 6) + ci] = ob;
    ((bf16x8*)xb)[(n << 6) + ci] = xbv;
}

// uv = relu(bn2([x, agg] @ W_vu)) : [8192,1024]@[1024,256], bf16 out
__global__ __launch_bounds__(256) void k_uv(
    const short* __restrict__ xb, const short* __restrict__ agg,
    const short* __restrict__ Bp, const float* __restrict__ P,
    short* __restrict__ uv)
{
    int lane = threadIdx.x & 63, wv = threadIdx.x >> 6;
    int r0 = blockIdx.x << 5;
    int wlane = lane & 15;
    int kseg = (lane >> 4) << 3;
    const bf16x8* Bpv = (const bf16x8*)Bp;

    f32x4 acc[2][4];
    #pragma unroll
    for (int m = 0; m < 2; ++m)
        #pragma unroll
        for (int nf = 0; nf < 4; ++nf) acc[m][nf] = (f32x4){0.f, 0.f, 0.f, 0.f};

    int arow0 = (r0 + wlane) << 9;
    int arow1 = (r0 + 16 + wlane) << 9;

    for (int kt = 0; kt < 32; ++kt) {
        const short* As = (kt < 16) ? xb : agg;
        int kloc = ((kt & 15) << 5) + kseg;
        bf16x8 a0 = *(const bf16x8*)(As + arow0 + kloc);
        bf16x8 a1 = *(const bf16x8*)(As + arow1 + kloc);
        #pragma unroll
        for (int nf = 0; nf < 4; ++nf) {
            bf16x8 b = Bpv[((((wv << 2) + nf) << 5) + kt) * 64 + lane];
            acc[0][nf] = __builtin_amdgcn_mfma_f32_16x16x32_bf16(a0, b, acc[0][nf], 0, 0, 0);
            acc[1][nf] = __builtin_amdgcn_mfma_f32_16x16x32_bf16(a1, b, acc[1][nf], 0, 0, 0);
        }
    }
    #pragma unroll
    for (int m = 0; m < 2; ++m)
        #pragma unroll
        for (int nf = 0; nf < 4; ++nf) {
            int col = (wv << 6) + (nf << 4) + wlane;
            float a2 = P[8 + col], c2 = P[264 + col];
            int rbase = r0 + (m << 4) + ((lane >> 4) << 2);
            #pragma unroll
            for (int j = 0; j < 4; ++j) {
                float v = fmaxf(fmaf(acc[m][nf][j], a2, c2), 0.f);
                uv[(rbase + j) * 256 + col] = f2bf(v);
            }
        }
}

// Fused edge-update + edge-reduce + vertex*edge product:
//   Tv = x @ Weu_top ;  Te_k = (x*neigh_k) @ Weu_bot
//   ue_k = relu(a3*(Tv+Te_k)+c3) ; ur = relu(a4*sum_k w_er[k]*ue_k + c4)
//   upd = uv * ur   (bf16 out)
__global__ __launch_bounds__(256) void k_edge(
    const short* __restrict__ xb, const short* __restrict__ Bp,
    const float* __restrict__ P, const short* __restrict__ uv,
    short* __restrict__ upd)
{
    int lane = threadIdx.x & 63, wv = threadIdx.x >> 6;
    int n0 = blockIdx.x << 5;
    int bh = n0 >> 6, h = bh & 63, bhb = bh & ~63;
    int rowBH = bh << 6, w0 = n0 & 63;
    int wlane = lane & 15;
    int kseg = (lane >> 4) << 3;
    int rowU = (bhb + ((h + 63) & 63)) << 6;
    int rowD = (bhb + ((h + 1) & 63)) << 6;
    const bf16x8* Bpv = (const bf16x8*)Bp;

    int wm0 = w0 + wlane, wm1 = w0 + 16 + wlane;
    int xr0 = (rowBH + wm0) << 9, xr1 = (rowBH + wm1) << 9;

    f32x4 accT[2][4];
    #pragma unroll
    for (int m = 0; m < 2; ++m)
        #pragma unroll
        for (int nf = 0; nf < 4; ++nf) accT[m][nf] = (f32x4){0.f, 0.f, 0.f, 0.f};

    for (int kt = 0; kt < 16; ++kt) {
        int kloc = (kt << 5) + kseg;
        bf16x8 a0 = *(const bf16x8*)(xb + xr0 + kloc);
        bf16x8 a1 = *(const bf16x8*)(xb + xr1 + kloc);
        #pragma unroll
        for (int nf = 0; nf < 4; ++nf) {
            bf16x8 b = Bpv[((((wv << 2) + nf) << 5) + kt) * 64 + lane];
            accT[0][nf] = __builtin_amdgcn_mfma_f32_16x16x32_bf16(a0, b, accT[0][nf], 0, 0, 0);
            accT[1][nf] = __builtin_amdgcn_mfma_f32_16x16x32_bf16(a1, b, accT[1][nf], 0, 0, 0);
        }
    }

    float a3v[4], c3v[4];
    #pragma unroll
    for (int nf = 0; nf < 4; ++nf) {
        int col = (wv << 6) + (nf << 4) + wlane;
        a3v[nf] = P[520 + col];
        c3v[nf] = P[776 + col];
    }

    f32x4 ur[2][4];
    #pragma unroll
    for (int m = 0; m < 2; ++m)
        #pragma unroll
        for (int nf = 0; nf < 4; ++nf) ur[m][nf] = (f32x4){0.f, 0.f, 0.f, 0.f};

    #pragma unroll
    for (int k = 0; k < 4; ++k) {
        int nr0, nr1;
        if (k == 0)      { nr0 = rowU + wm0;                nr1 = rowU + wm1; }
        else if (k == 1) { nr0 = rowD + wm0;                nr1 = rowD + wm1; }
        else if (k == 2) { nr0 = rowBH + ((wm0 + 63) & 63); nr1 = rowBH + ((wm1 + 63) & 63); }
        else             { nr0 = rowBH + ((wm0 + 1) & 63);  nr1 = rowBH + ((wm1 + 1) & 63); }
        nr0 <<= 9; nr1 <<= 9;

        f32x4 accE[2][4];
        #pragma unroll
        for (int m = 0; m < 2; ++m)
            #pragma unroll
            for (int nf = 0; nf < 4; ++nf) accE[m][nf] = (f32x4){0.f, 0.f, 0.f, 0.f};

        for (int kt = 0; kt < 16; ++kt) {
            int kloc = (kt << 5) + kseg;
            bf16x8 xa0 = *(const bf16x8*)(xb + xr0 + kloc);
            bf16x8 na0 = *(const bf16x8*)(xb + nr0 + kloc);
            bf16x8 xa1 = *(const bf16x8*)(xb + xr1 + kloc);
            bf16x8 na1 = *(const bf16x8*)(xb + nr1 + kloc);
            bf16x8 a0, a1;
            #pragma unroll
            for (int j = 0; j < 8; ++j) {
                a0[j] = f2bf(bf2f(xa0[j]) * bf2f(na0[j]));
                a1[j] = f2bf(bf2f(xa1[j]) * bf2f(na1[j]));
            }
            #pragma unroll
            for (int nf = 0; nf < 4; ++nf) {
                bf16x8 b = Bpv[((((wv << 2) + nf) << 5) + 16 + kt) * 64 + lane];
                accE[0][nf] = __builtin_amdgcn_mfma_f32_16x16x32_bf16(a0, b, accE[0][nf], 0, 0, 0);
                accE[1][nf] = __builtin_amdgcn_mfma_f32_16x16x32_bf16(a1, b, accE[1][nf], 0, 0, 0);
            }
        }
        float wk = P[2060 + k];
        #pragma unroll
        for (int m = 0; m < 2; ++m)
            #pragma unroll
            for (int nf = 0; nf < 4; ++nf)
                #pragma unroll
                for (int j = 0; j < 4; ++j) {
                    float z = accT[m][nf][j] + accE[m][nf][j];
                    ur[m][nf][j] += wk * fmaxf(fmaf(a3v[nf], z, c3v[nf]), 0.f);
                }
    }

    float a4 = P[2], c4 = P[3];
    #pragma unroll
    for (int m = 0; m < 2; ++m)
        #pragma unroll
        for (int nf = 0; nf < 4; ++nf) {
            int col = (wv << 6) + (nf << 4) + wlane;
            int rbase = n0 + (m << 4) + ((lane >> 4) << 2);
            #pragma unroll
            for (int j = 0; j < 4; ++j) {
                float urv = fmaxf(fmaf(a4, ur[m][nf][j], c4), 0.f);
                float uvv = bf2f(uv[(rbase + j) * 256 + col]);
                upd[(rbase + j) * 256 + col] = f2bf(urv * uvv);
            }
        }
}

// out = relu(bn5([x, upd] @ W_fc)) : [8192,768]@[768,512], f32 out
__global__ __launch_bounds__(256) void k_out(
    const short* __restrict__ xb, const short* __restrict__ upd,
    const short* __restrict__ Bp, const float* __restrict__ P,
    float* __restrict__ out)
{
    int lane = threadIdx.x & 63, wv = threadIdx.x >> 6;
    int rb = blockIdx.x >> 1, cg = blockIdx.x & 1;
    int r0 = rb << 5;
    int wlane = lane & 15;
    int kseg = (lane >> 4) << 3;
    int ntb = (cg << 4) + (wv << 2);       // global 16-col tile index base
    const bf16x8* Bpv = (const bf16x8*)Bp;

    f32x4 acc[2][4];
    #pragma unroll
    for (int m = 0; m < 2; ++m)
        #pragma unroll
        for (int nf = 0; nf < 4; ++nf) acc[m][nf] = (f32x4){0.f, 0.f, 0.f, 0.f};

    int xr0 = (r0 + wlane) << 9, xr1 = (r0 + 16 + wlane) << 9;
    int ur0 = (r0 + wlane) << 8, ur1 = (r0 + 16 + wlane) << 8;

    for (int kt = 0; kt < 24; ++kt) {
        bf16x8 a0, a1;
        if (kt < 16) {
            int kloc = (kt << 5) + kseg;
            a0 = *(const bf16x8*)(xb + xr0 + kloc);
            a1 = *(const bf16x8*)(xb + xr1 + kloc);
        } else {
            int kloc = ((kt - 16) << 5) + kseg;
            a0 = *(const bf16x8*)(upd + ur0 + kloc);
            a1 = *(const bf16x8*)(upd + ur1 + kloc);
        }
        #pragma unroll
        for (int nf = 0; nf < 4; ++nf) {
            bf16x8 b = Bpv[((ntb + nf) * 24 + kt) * 64 + lane];
            acc[0][nf] = __builtin_amdgcn_mfma_f32_16x16x32_bf16(a0, b, acc[0][nf], 0, 0, 0);
            acc[1][nf] = __builtin_amdgcn_mfma_f32_16x16x32_bf16(a1, b, acc[1][nf], 0, 0, 0);
        }
    }
    #pragma unroll
    for (int m = 0; m < 2; ++m)
        #pragma unroll
        for (int nf = 0; nf < 4; ++nf) {
            int col = (cg << 8) + (wv << 6) + (nf << 4) + wlane;
            float a5 = P[1032 + col], c5 = P[1544 + col];
            int rbase = r0 + (m << 4) + ((lane >> 4) << 2);
            #pragma unroll
            for (int j = 0; j < 4; ++j) {
                out[(rbase + j) * 512 + col] = fmaxf(fmaf(acc[m][nf][j], a5, c5), 0.f);
            }
        }
}

extern "C" void kernel_launch(void* const* d_in, const int* in_sizes, int n_in,
                              void* d_out, int out_size, void* d_ws, size_t ws_size,
                              hipStream_t stream)
{
    const float* x    = (const float*)d_in[0];
    const float* w_ea = (const float*)d_in[1];
    const float* b_ea = (const float*)d_in[2];
    const float* g1   = (const float*)d_in[3];
    const float* b1   = (const float*)d_in[4];
    const float* m1   = (const float*)d_in[5];
    const float* v1   = (const float*)d_in[6];
    const float* w_vu = (const float*)d_in[7];
    const float* b_vu = (const float*)d_in[8];
    const float* g2   = (const float*)d_in[9];
    const float* b2   = (const float*)d_in[10];
    const float* m2   = (const float*)d_in[11];
    const float* v2   = (const float*)d_in[12];
    const float* w_eu = (const float*)d_in[13];
    const float* b_eu = (const float*)d_in[14];
    const float* g3   = (const float*)d_in[15];
    const float* b3   = (const float*)d_in[16];
    const float* m3   = (const float*)d_in[17];
    const float* v3   = (const float*)d_in[18];
    const float* w_er = (const float*)d_in[19];
    const float* b_er = (const float*)d_in[20];
    const float* g4   = (const float*)d_in[21];
    const float* b4   = (const float*)d_in[22];
    const float* m4   = (const float*)d_in[23];
    const float* v4   = (const float*)d_in[24];
    const float* w_fc = (const float*)d_in[25];
    const float* g5   = (const float*)d_in[26];
    const float* b5   = (const float*)d_in[27];
    const float* m5   = (const float*)d_in[28];
    const float* v5   = (const float*)d_in[29];

    char* ws = (char*)d_ws;
    float* P = (float*)ws;
    size_t off = 16384;
    short* BpVu = (short*)(ws + off); off += (size_t)1024 * 256 * 2;
    short* BpEu = (short*)(ws + off); off += (size_t)1024 * 256 * 2;
    short* BpFc = (short*)(ws + off); off += (size_t)768 * 512 * 2;
    short* xbb  = (short*)(ws + off); off += (size_t)8192 * 512 * 2;
    short* aggb = (short*)(ws + off); off += (size_t)8192 * 512 * 2;
    short* uvb  = (short*)(ws + off); off += (size_t)8192 * 256 * 2;
    short* updb = (short*)(ws + off); off += (size_t)8192 * 256 * 2;

    prep_params<<<1, 512, 0, stream>>>(w_ea, b_ea, g1, b1, m1, v1,
                                       b_vu, g2, b2, m2, v2,
                                       b_eu, g3, b3, m3, v3,
                                       w_er, b_er, g4, b4, m4, v4,
                                       g5, b5, m5, v5, P);
    k_pack<<<128, 256, 0, stream>>>(w_vu, BpVu, 1024, 256);
    k_pack<<<128, 256, 0, stream>>>(w_eu, BpEu, 1024, 256);
    k_pack<<<192, 256, 0, stream>>>(w_fc, BpFc, 768, 512);
    k_cvt_agg<<<2048, 256, 0, stream>>>(x, P, xbb, aggb);
    k_uv<<<256, 256, 0, stream>>>(xbb, aggb, BpVu, P, uvb);
    k_edge<<<256, 256, 0, stream>>>(xbb, BpEu, P, uvb, updb);
    k_out<<<512, 256, 0, stream>>>(xbb, updb, BpFc, P, (float*)d_out);
}

// Round 3
// 113.825 us; speedup vs baseline: 1.2807x; 1.2807x over previous
//
#include <hip/hip_runtime.h>
#include <stdint.h>

// ---------------------------------------------------------------------------
// GraphBasedSkipConnection, MI355X. f32 I/O; bf16 MFMA GEMMs internally.
//   B=2, H=64, W=64, C=512, C2=256, N = 8192 pixels.
// Round 3: edge products materialized in the stencil kernel (kills the
// in-GEMM VALU pack), uv+edge fused into one pure-GEMM kernel, occupancy
// raised via N-split blocks.
// ---------------------------------------------------------------------------

typedef __attribute__((ext_vector_type(8))) short bf16x8;
typedef __attribute__((ext_vector_type(4))) float f32x4;

#define EPS_BN 1e-3f

__device__ __forceinline__ short f2bf(float f) {
    union { float f; unsigned u; } cv;
    cv.f = f;
    unsigned r = cv.u + 0x7fffu + ((cv.u >> 16) & 1u);
    return (short)(r >> 16);
}
__device__ __forceinline__ float bf2f(short s) {
    union { unsigned u; float f; } cv;
    cv.u = ((unsigned)(unsigned short)s) << 16;
    return cv.f;
}

// ---- P layout (floats) -----------------------------------------------------
// 0 a1, 1 c1, 2 a4, 3 c4
// 8..264    a2[256]     264..520  c2[256]
// 520..776  a3[256]     776..1032 c3[256]
// 1032..1544 a5[512]    1544..2056 c5[512]
// 2056..2060 w_ea[4]    2060..2064 w_er[4]
// ---------------------------------------------------------------------------

// Pack W[K, Ncol] (row-major f32) into bf16 MFMA B-fragment order:
// tile = nt*(K/32)+kt ; packed[(tile*64+lane)*8+j] = W[kt*32+(lane>>4)*8+j][nt*16+(lane&15)]
__device__ __forceinline__ void pack_one(const float* __restrict__ W, short* __restrict__ out,
                                         int K, int Ncol, int lb, int tid) {
    int i = lb * 256 + tid;
    int lane = i & 63, tile = i >> 6;
    int ktiles = K >> 5;
    int nt = tile / ktiles, kt = tile - nt * ktiles;
    int kbase = (kt << 5) + ((lane >> 4) << 3);
    int col = (nt << 4) + (lane & 15);
    bf16x8 v;
    #pragma unroll
    for (int j = 0; j < 8; ++j) v[j] = f2bf(W[(kbase + j) * Ncol + col]);
    ((bf16x8*)out)[(tile << 6) + lane] = v;
}

// blocks 0..127 pack W_vu, 128..255 W_eu, 256..447 W_fc, 448 computes P
__global__ __launch_bounds__(256) void k_setup(
    const float* w_vu, const float* w_eu, const float* w_fc,
    short* BpVu, short* BpEu, short* BpFc,
    const float* w_ea, const float* b_ea,
    const float* g1, const float* b1, const float* m1, const float* v1,
    const float* b_vu,
    const float* g2, const float* b2, const float* m2, const float* v2,
    const float* b_eu,
    const float* g3, const float* b3, const float* m3, const float* v3,
    const float* w_er, const float* b_er,
    const float* g4, const float* b4, const float* m4, const float* v4,
    const float* g5, const float* b5, const float* m5, const float* v5,
    float* P)
{
    int b = blockIdx.x, t = threadIdx.x;
    if (b < 128)      { pack_one(w_vu, BpVu, 1024, 256, b, t); }
    else if (b < 256) { pack_one(w_eu, BpEu, 1024, 256, b - 128, t); }
    else if (b < 448) { pack_one(w_fc, BpFc,  768, 512, b - 256, t); }
    else {
        for (int u = t; u < 512; u += 256) {
            float a5 = g5[u] * rsqrtf(v5[u] + EPS_BN);
            P[1032 + u] = a5;
            P[1544 + u] = b5[u] - m5[u] * a5;          // w_fc has no bias
        }
        {
            float a2 = g2[t] * rsqrtf(v2[t] + EPS_BN);
            P[8 + t]   = a2;
            P[264 + t] = (b_vu[t] - m2[t]) * a2 + b2[t];
            float a3 = g3[t] * rsqrtf(v3[t] + EPS_BN);
            P[520 + t] = a3;
            P[776 + t] = (b_eu[t] - m3[t]) * a3 + b3[t];
        }
        if (t < 4) {
            P[2056 + t] = w_ea[t];
            P[2060 + t] = w_er[t];
        }
        if (t == 0) {
            float a1 = g1[0] * rsqrtf(v1[0] + EPS_BN);
            P[0] = a1;
            P[1] = (b_ea[0] - m1[0]) * a1 + b1[0];
            float a4 = g4[0] * rsqrtf(v4[0] + EPS_BN);
            P[2] = a4;
            P[3] = (b_er[0] - m4[0]) * a4 + b4[0];
        }
    }
}

// Fused stencil kernel:
//   xb     = bf16(x)
//   prod_k = bf16(x * neigh_k)                              k = U,D,L,R
//   agg    = bf16(relu(a1 * sum_k(w_ea[k] * x*neigh_k) + c1))
__global__ __launch_bounds__(256) void k_cvt_agg(const float* __restrict__ x,
                                                 const float* __restrict__ P,
                                                 short* __restrict__ xb,
                                                 short* __restrict__ agg,
                                                 short* __restrict__ prod)
{
    int idx = blockIdx.x * 256 + threadIdx.x;   // N*C/8 threads
    int n = idx >> 6;
    int ci = idx & 63;                          // channel group of 8
    int bh = n >> 6, h = bh & 63, w = n & 63;
    int bhb = bh & ~63;
    int rowU = ((bhb + ((h + 63) & 63)) << 6) + w;
    int rowD = ((bhb + ((h + 1) & 63)) << 6) + w;
    int rowL = (bh << 6) + ((w + 63) & 63);
    int rowR = (bh << 6) + ((w + 1) & 63);

    const f32x4* xv = (const f32x4*)x;
    int c4 = ci << 1;
    f32x4 vc[2], vU[2], vD[2], vL[2], vR[2];
    #pragma unroll
    for (int h2 = 0; h2 < 2; ++h2) {
        vc[h2] = xv[(n    << 7) + c4 + h2];
        vU[h2] = xv[(rowU << 7) + c4 + h2];
        vD[h2] = xv[(rowD << 7) + c4 + h2];
        vL[h2] = xv[(rowL << 7) + c4 + h2];
        vR[h2] = xv[(rowR << 7) + c4 + h2];
    }

    float w0 = P[2056], w1 = P[2057], w2 = P[2058], w3 = P[2059];
    float a1 = P[0], c1 = P[1];
    bf16x8 ob, xbv, pU, pD, pL, pR;
    #pragma unroll
    for (int h2 = 0; h2 < 2; ++h2) {
        #pragma unroll
        for (int j = 0; j < 4; ++j) {
            int e = h2 * 4 + j;
            float xc = vc[h2][j];
            float eU = xc * vU[h2][j], eD = xc * vD[h2][j];
            float eL = xc * vL[h2][j], eR = xc * vR[h2][j];
            float S = w0 * eU + w1 * eD + w2 * eL + w3 * eR;
            ob[e]  = f2bf(fmaxf(fmaf(a1, S, c1), 0.f));
            xbv[e] = f2bf(xc);
            pU[e] = f2bf(eU); pD[e] = f2bf(eD);
            pL[e] = f2bf(eL); pR[e] = f2bf(eR);
        }
    }
    int o = (n << 6) + ci;
    const int PSTRIDE = 8192 * 64;              // in bf16x8 units
    ((bf16x8*)agg)[o] = ob;
    ((bf16x8*)xb)[o] = xbv;
    ((bf16x8*)prod)[o]               = pU;
    ((bf16x8*)prod)[o + PSTRIDE]     = pD;
    ((bf16x8*)prod)[o + 2 * PSTRIDE] = pL;
    ((bf16x8*)prod)[o + 3 * PSTRIDE] = pR;
}

// Fused middle kernel (pure GEMMs, no packing):
//   uv  = relu(bn2([xb, agg] @ W_vu))                    K=1024, N=256
//   Tv  = xb @ Weu_top ; Te_k = prod_k @ Weu_bot         K=512 each
//   ur  = relu(a4 * sum_k w_er[k]*relu(a3*(Tv+Te_k)+c3) + c4)
//   upd = uv * ur    (bf16)
// grid: (8192/32 rows) x 2 col-halves = 512 blocks, 4 waves, wave = 32r x 32c
__global__ __launch_bounds__(256) void k_mid(
    const short* __restrict__ xb, const short* __restrict__ agg,
    const short* __restrict__ prod,
    const short* __restrict__ BpVu, const short* __restrict__ BpEu,
    const float* __restrict__ P,
    short* __restrict__ upd)
{
    int lane = threadIdx.x & 63, wv = threadIdx.x >> 6;
    int rb = blockIdx.x >> 1, cg = blockIdx.x & 1;
    int r0 = rb << 5;
    int wlane = lane & 15;
    int kseg = (lane >> 4) << 3;
    int nt0 = (cg << 3) + (wv << 1);            // base 16-col tile (of 16)
    const bf16x8* Bv = (const bf16x8*)BpVu;
    const bf16x8* Be = (const bf16x8*)BpEu;

    int xr0 = (r0 + wlane) << 9, xr1 = (r0 + 16 + wlane) << 9;

    // ---- phase 1: uv ----
    f32x4 acc[2][2];
    #pragma unroll
    for (int m = 0; m < 2; ++m)
        #pragma unroll
        for (int nf = 0; nf < 2; ++nf) acc[m][nf] = (f32x4){0.f, 0.f, 0.f, 0.f};

    for (int kt = 0; kt < 32; ++kt) {
        const short* As = (kt < 16) ? xb : agg;
        int kloc = ((kt & 15) << 5) + kseg;
        bf16x8 a0 = *(const bf16x8*)(As + xr0 + kloc);
        bf16x8 a1 = *(const bf16x8*)(As + xr1 + kloc);
        #pragma unroll
        for (int nf = 0; nf < 2; ++nf) {
            bf16x8 b = Bv[(((nt0 + nf) << 5) + kt) * 64 + lane];
            acc[0][nf] = __builtin_amdgcn_mfma_f32_16x16x32_bf16(a0, b, acc[0][nf], 0, 0, 0);
            acc[1][nf] = __builtin_amdgcn_mfma_f32_16x16x32_bf16(a1, b, acc[1][nf], 0, 0, 0);
        }
    }
    float uvv[2][2][4];
    #pragma unroll
    for (int nf = 0; nf < 2; ++nf) {
        int col = ((nt0 + nf) << 4) + wlane;
        float a2 = P[8 + col], c2 = P[264 + col];
        #pragma unroll
        for (int m = 0; m < 2; ++m)
            #pragma unroll
            for (int j = 0; j < 4; ++j)
                uvv[m][nf][j] = fmaxf(fmaf(acc[m][nf][j], a2, c2), 0.f);
    }

    // ---- phase 2: edge top (Tv) ----
    f32x4 accT[2][2];
    #pragma unroll
    for (int m = 0; m < 2; ++m)
        #pragma unroll
        for (int nf = 0; nf < 2; ++nf) accT[m][nf] = (f32x4){0.f, 0.f, 0.f, 0.f};

    for (int kt = 0; kt < 16; ++kt) {
        int kloc = (kt << 5) + kseg;
        bf16x8 a0 = *(const bf16x8*)(xb + xr0 + kloc);
        bf16x8 a1 = *(const bf16x8*)(xb + xr1 + kloc);
        #pragma unroll
        for (int nf = 0; nf < 2; ++nf) {
            bf16x8 b = Be[(((nt0 + nf) << 5) + kt) * 64 + lane];
            accT[0][nf] = __builtin_amdgcn_mfma_f32_16x16x32_bf16(a0, b, accT[0][nf], 0, 0, 0);
            accT[1][nf] = __builtin_amdgcn_mfma_f32_16x16x32_bf16(a1, b, accT[1][nf], 0, 0, 0);
        }
    }

    float a3v[2], c3v[2];
    #pragma unroll
    for (int nf = 0; nf < 2; ++nf) {
        int col = ((nt0 + nf) << 4) + wlane;
        a3v[nf] = P[520 + col];
        c3v[nf] = P[776 + col];
    }

    f32x4 ur[2][2];
    #pragma unroll
    for (int m = 0; m < 2; ++m)
        #pragma unroll
        for (int nf = 0; nf < 2; ++nf) ur[m][nf] = (f32x4){0.f, 0.f, 0.f, 0.f};

    // ---- phase 2b: per-neighbor edge GEMMs ----
    #pragma unroll 1
    for (int k = 0; k < 4; ++k) {
        const short* Pk = prod + (size_t)k * 8192 * 512;
        f32x4 accE[2][2];
        #pragma unroll
        for (int m = 0; m < 2; ++m)
            #pragma unroll
            for (int nf = 0; nf < 2; ++nf) accE[m][nf] = (f32x4){0.f, 0.f, 0.f, 0.f};

        for (int kt = 0; kt < 16; ++kt) {
            int kloc = (kt << 5) + kseg;
            bf16x8 a0 = *(const bf16x8*)(Pk + xr0 + kloc);
            bf16x8 a1 = *(const bf16x8*)(Pk + xr1 + kloc);
            #pragma unroll
            for (int nf = 0; nf < 2; ++nf) {
                bf16x8 b = Be[(((nt0 + nf) << 5) + 16 + kt) * 64 + lane];
                accE[0][nf] = __builtin_amdgcn_mfma_f32_16x16x32_bf16(a0, b, accE[0][nf], 0, 0, 0);
                accE[1][nf] = __builtin_amdgcn_mfma_f32_16x16x32_bf16(a1, b, accE[1][nf], 0, 0, 0);
            }
        }
        float wk = P[2060 + k];
        #pragma unroll
        for (int m = 0; m < 2; ++m)
            #pragma unroll
            for (int nf = 0; nf < 2; ++nf)
                #pragma unroll
                for (int j = 0; j < 4; ++j) {
                    float z = accT[m][nf][j] + accE[m][nf][j];
                    ur[m][nf][j] += wk * fmaxf(fmaf(a3v[nf], z, c3v[nf]), 0.f);
                }
    }

    // ---- phase 3: upd = uv * relu(a4*ur + c4) ----
    float a4 = P[2], c4 = P[3];
    #pragma unroll
    for (int m = 0; m < 2; ++m)
        #pragma unroll
        for (int nf = 0; nf < 2; ++nf) {
            int col = ((nt0 + nf) << 4) + wlane;
            int rbase = r0 + (m << 4) + ((lane >> 4) << 2);
            #pragma unroll
            for (int j = 0; j < 4; ++j) {
                float urv = fmaxf(fmaf(a4, ur[m][nf][j], c4), 0.f);
                upd[(rbase + j) * 256 + col] = f2bf(urv * uvv[m][nf][j]);
            }
        }
}

// out = relu(bn5([xb, upd] @ W_fc)) : [8192,768]@[768,512], f32 out
// grid: (8192/32 rows) x 4 col-quarters = 1024 blocks, wave = 32r x 32c
__global__ __launch_bounds__(256) void k_out(
    const short* __restrict__ xb, const short* __restrict__ upd,
    const short* __restrict__ BpFc, const float* __restrict__ P,
    float* __restrict__ out)
{
    int lane = threadIdx.x & 63, wv = threadIdx.x >> 6;
    int rb = blockIdx.x >> 2, cg = blockIdx.x & 3;
    int r0 = rb << 5;
    int wlane = lane & 15;
    int kseg = (lane >> 4) << 3;
    int ntb = (cg << 3) + (wv << 1);            // base 16-col tile (of 32)
    const bf16x8* Bpv = (const bf16x8*)BpFc;

    f32x4 acc[2][2];
    #pragma unroll
    for (int m = 0; m < 2; ++m)
        #pragma unroll
        for (int nf = 0; nf < 2; ++nf) acc[m][nf] = (f32x4){0.f, 0.f, 0.f, 0.f};

    int xr0 = (r0 + wlane) << 9, xr1 = (r0 + 16 + wlane) << 9;
    int ur0 = (r0 + wlane) << 8, ur1 = (r0 + 16 + wlane) << 8;

    for (int kt = 0; kt < 24; ++kt) {
        bf16x8 a0, a1;
        if (kt < 16) {
            int kloc = (kt << 5) + kseg;
            a0 = *(const bf16x8*)(xb + xr0 + kloc);
            a1 = *(const bf16x8*)(xb + xr1 + kloc);
        } else {
            int kloc = ((kt - 16) << 5) + kseg;
            a0 = *(const bf16x8*)(upd + ur0 + kloc);
            a1 = *(const bf16x8*)(upd + ur1 + kloc);
        }
        #pragma unroll
        for (int nf = 0; nf < 2; ++nf) {
            bf16x8 b = Bpv[((ntb + nf) * 24 + kt) * 64 + lane];
            acc[0][nf] = __builtin_amdgcn_mfma_f32_16x16x32_bf16(a0, b, acc[0][nf], 0, 0, 0);
            acc[1][nf] = __builtin_amdgcn_mfma_f32_16x16x32_bf16(a1, b, acc[1][nf], 0, 0, 0);
        }
    }
    #pragma unroll
    for (int m = 0; m < 2; ++m)
        #pragma unroll
        for (int nf = 0; nf < 2; ++nf) {
            int col = ((ntb + nf) << 4) + wlane;
            float a5 = P[1032 + col], c5 = P[1544 + col];
            int rbase = r0 + (m << 4) + ((lane >> 4) << 2);
            #pragma unroll
            for (int j = 0; j < 4; ++j) {
                out[(rbase + j) * 512 + col] = fmaxf(fmaf(acc[m][nf][j], a5, c5), 0.f);
            }
        }
}

extern "C" void kernel_launch(void* const* d_in, const int* in_sizes, int n_in,
                              void* d_out, int out_size, void* d_ws, size_t ws_size,
                              hipStream_t stream)
{
    const float* x    = (const float*)d_in[0];
    const float* w_ea = (const float*)d_in[1];
    const float* b_ea = (const float*)d_in[2];
    const float* g1   = (const float*)d_in[3];
    const float* b1   = (const float*)d_in[4];
    const float* m1   = (const float*)d_in[5];
    const float* v1   = (const float*)d_in[6];
    const float* w_vu = (const float*)d_in[7];
    const float* b_vu = (const float*)d_in[8];
    const float* g2   = (const float*)d_in[9];
    const float* b2   = (const float*)d_in[10];
    const float* m2   = (const float*)d_in[11];
    const float* v2   = (const float*)d_in[12];
    const float* w_eu = (const float*)d_in[13];
    const float* b_eu = (const float*)d_in[14];
    const float* g3   = (const float*)d_in[15];
    const float* b3   = (const float*)d_in[16];
    const float* m3   = (const float*)d_in[17];
    const float* v3   = (const float*)d_in[18];
    const float* w_er = (const float*)d_in[19];
    const float* b_er = (const float*)d_in[20];
    const float* g4   = (const float*)d_in[21];
    const float* b4   = (const float*)d_in[22];
    const float* m4   = (const float*)d_in[23];
    const float* v4   = (const float*)d_in[24];
    const float* w_fc = (const float*)d_in[25];
    const float* g5   = (const float*)d_in[26];
    const float* b5   = (const float*)d_in[27];
    const float* m5   = (const float*)d_in[28];
    const float* v5   = (const float*)d_in[29];

    char* ws = (char*)d_ws;
    float* P = (float*)ws;
    size_t off = 16384;
    short* BpVu = (short*)(ws + off); off += (size_t)1024 * 256 * 2;
    short* BpEu = (short*)(ws + off); off += (size_t)1024 * 256 * 2;
    short* BpFc = (short*)(ws + off); off += (size_t)768 * 512 * 2;
    short* xbb  = (short*)(ws + off); off += (size_t)8192 * 512 * 2;
    short* aggb = (short*)(ws + off); off += (size_t)8192 * 512 * 2;
    short* prod = (short*)(ws + off); off += (size_t)4 * 8192 * 512 * 2;
    short* updb = (short*)(ws + off); off += (size_t)8192 * 256 * 2;

    k_setup<<<449, 256, 0, stream>>>(w_vu, w_eu, w_fc, BpVu, BpEu, BpFc,
                                     w_ea, b_ea, g1, b1, m1, v1,
                                     b_vu, g2, b2, m2, v2,
                                     b_eu, g3, b3, m3, v3,
                                     w_er, b_er, g4, b4, m4, v4,
                                     g5, b5, m5, v5, P);
    k_cvt_agg<<<2048, 256, 0, stream>>>(x, P, xbb, aggb, prod);
    k_mid<<<512, 256, 0, stream>>>(xbb, aggb, prod, BpVu, BpEu, P, updb);
    k_out<<<1024, 256, 0, stream>>>(xbb, updb, BpFc, P, (float*)d_out);
}

// Round 4
// 75.954 us; speedup vs baseline: 1.9193x; 1.4986x over previous
//
#include <hip/hip_runtime.h>
#include <stdint.h>

// ---------------------------------------------------------------------------
// GraphBasedSkipConnection, MI355X. f32 I/O; bf16 MFMA GEMMs internally.
//   B=2, H=64, W=64, C=512, C2=256, N = 8192 pixels.
// Round 4:
//  - prod_U/prod_L are shifted copies of prod_D/prod_R -> only 2 edge GEMMs
//    (TeD, TeR); ue_U/ue_L read them at cyclically shifted pixels (k_ur_upd).
//  - GEMMs restructured: one accumulator group per block, A staged in LDS
//    (XOR-swizzled, double-buffered, 1 barrier/iter), B coalesced from L2.
// ---------------------------------------------------------------------------

typedef __attribute__((ext_vector_type(8))) short bf16x8;
typedef __attribute__((ext_vector_type(4))) float f32x4;

#define EPS_BN 1e-3f

__device__ __forceinline__ short f2bf(float f) {
    union { float f; unsigned u; } cv;
    cv.f = f;
    unsigned r = cv.u + 0x7fffu + ((cv.u >> 16) & 1u);
    return (short)(r >> 16);
}
__device__ __forceinline__ float bf2f(short s) {
    union { unsigned u; float f; } cv;
    cv.u = ((unsigned)(unsigned short)s) << 16;
    return cv.f;
}

// ---- P layout (floats) -----------------------------------------------------
// 0 a1, 1 c1, 2 a4, 3 c4
// 8..264    a2[256]     264..520  c2[256]
// 520..776  a3[256]     776..1032 c3[256]
// 1032..1544 a5[512]    1544..2056 c5[512]
// 2056..2060 w_ea[4]    2060..2064 w_er[4]
// ---------------------------------------------------------------------------

// Pack W[K, Ncol] (row-major f32) into bf16 MFMA B-fragment order:
// tile = nt*(K/32)+kt ; packed[(tile*64+lane)*8+j] = W[kt*32+(lane>>4)*8+j][nt*16+(lane&15)]
__device__ __forceinline__ void pack_one(const float* __restrict__ W, short* __restrict__ out,
                                         int K, int Ncol, int lb, int tid) {
    int i = lb * 256 + tid;
    int lane = i & 63, tile = i >> 6;
    int ktiles = K >> 5;
    int nt = tile / ktiles, kt = tile - nt * ktiles;
    int kbase = (kt << 5) + ((lane >> 4) << 3);
    int col = (nt << 4) + (lane & 15);
    bf16x8 v;
    #pragma unroll
    for (int j = 0; j < 8; ++j) v[j] = f2bf(W[(kbase + j) * Ncol + col]);
    ((bf16x8*)out)[(tile << 6) + lane] = v;
}

// blocks 0..127 pack W_vu, 128..255 W_eu, 256..447 W_fc, 448 computes P
__global__ __launch_bounds__(256) void k_setup(
    const float* w_vu, const float* w_eu, const float* w_fc,
    short* BpVu, short* BpEu, short* BpFc,
    const float* w_ea, const float* b_ea,
    const float* g1, const float* b1, const float* m1, const float* v1,
    const float* b_vu,
    const float* g2, const float* b2, const float* m2, const float* v2,
    const float* b_eu,
    const float* g3, const float* b3, const float* m3, const float* v3,
    const float* w_er, const float* b_er,
    const float* g4, const float* b4, const float* m4, const float* v4,
    const float* g5, const float* b5, const float* m5, const float* v5,
    float* P)
{
    int b = blockIdx.x, t = threadIdx.x;
    if (b < 128)      { pack_one(w_vu, BpVu, 1024, 256, b, t); }
    else if (b < 256) { pack_one(w_eu, BpEu, 1024, 256, b - 128, t); }
    else if (b < 448) { pack_one(w_fc, BpFc,  768, 512, b - 256, t); }
    else {
        for (int u = t; u < 512; u += 256) {
            float a5 = g5[u] * rsqrtf(v5[u] + EPS_BN);
            P[1032 + u] = a5;
            P[1544 + u] = b5[u] - m5[u] * a5;          // w_fc has no bias
        }
        {
            float a2 = g2[t] * rsqrtf(v2[t] + EPS_BN);
            P[8 + t]   = a2;
            P[264 + t] = (b_vu[t] - m2[t]) * a2 + b2[t];
            float a3 = g3[t] * rsqrtf(v3[t] + EPS_BN);
            P[520 + t] = a3;
            P[776 + t] = (b_eu[t] - m3[t]) * a3 + b3[t];
        }
        if (t < 4) {
            P[2056 + t] = w_ea[t];
            P[2060 + t] = w_er[t];
        }
        if (t == 0) {
            float a1 = g1[0] * rsqrtf(v1[0] + EPS_BN);
            P[0] = a1;
            P[1] = (b_ea[0] - m1[0]) * a1 + b1[0];
            float a4 = g4[0] * rsqrtf(v4[0] + EPS_BN);
            P[2] = a4;
            P[3] = (b_er[0] - m4[0]) * a4 + b4[0];
        }
    }
}

// Fused stencil kernel:
//   xb    = bf16(x)
//   prodD = bf16(x * x[h+1]),  prodR = bf16(x * x[w+1])
//   agg   = bf16(relu(a1 * sum_k(w_ea[k] * x*neigh_k) + c1))
__global__ __launch_bounds__(256) void k_cvt_agg(const float* __restrict__ x,
                                                 const float* __restrict__ P,
                                                 short* __restrict__ xb,
                                                 short* __restrict__ agg,
                                                 short* __restrict__ prodD,
                                                 short* __restrict__ prodR)
{
    int idx = blockIdx.x * 256 + threadIdx.x;   // N*C/8 threads
    int n = idx >> 6;
    int ci = idx & 63;
    int bh = n >> 6, h = bh & 63, w = n & 63;
    int bhb = bh & ~63;
    int rowU = ((bhb + ((h + 63) & 63)) << 6) + w;
    int rowD = ((bhb + ((h + 1) & 63)) << 6) + w;
    int rowL = (bh << 6) + ((w + 63) & 63);
    int rowR = (bh << 6) + ((w + 1) & 63);

    const f32x4* xv = (const f32x4*)x;
    int c4 = ci << 1;
    f32x4 vc[2], vU[2], vD[2], vL[2], vR[2];
    #pragma unroll
    for (int h2 = 0; h2 < 2; ++h2) {
        vc[h2] = xv[(n    << 7) + c4 + h2];
        vU[h2] = xv[(rowU << 7) + c4 + h2];
        vD[h2] = xv[(rowD << 7) + c4 + h2];
        vL[h2] = xv[(rowL << 7) + c4 + h2];
        vR[h2] = xv[(rowR << 7) + c4 + h2];
    }

    float w0 = P[2056], w1 = P[2057], w2 = P[2058], w3 = P[2059];
    float a1 = P[0], c1 = P[1];
    bf16x8 ob, xbv, pD, pR;
    #pragma unroll
    for (int h2 = 0; h2 < 2; ++h2) {
        #pragma unroll
        for (int j = 0; j < 4; ++j) {
            int e = h2 * 4 + j;
            float xc = vc[h2][j];
            float eU = xc * vU[h2][j], eD = xc * vD[h2][j];
            float eL = xc * vL[h2][j], eR = xc * vR[h2][j];
            float S = w0 * eU + w1 * eD + w2 * eL + w3 * eR;
            ob[e]  = f2bf(fmaxf(fmaf(a1, S, c1), 0.f));
            xbv[e] = f2bf(xc);
            pD[e] = f2bf(eD); pR[e] = f2bf(eR);
        }
    }
    int o = (n << 6) + ci;
    ((bf16x8*)agg)[o] = ob;
    ((bf16x8*)xb)[o] = xbv;
    ((bf16x8*)prodD)[o] = pD;
    ((bf16x8*)prodR)[o] = pR;
}

// Unified middle GEMMs, one output type per block:
//   type 0: uv  = relu(bn2([xb,agg] @ W_vu))    K=1024
//   type 1: Tv  = xb    @ Weu_top               K=512  (raw bf16)
//   type 2: TeD = prodD @ Weu_bot               K=512  (raw bf16)
//   type 3: TeR = prodR @ Weu_bot               K=512  (raw bf16)
// block: 64 rows x 256 cols, 4 waves (wave = 64x64), A staged in LDS
// (XOR swizzle (row&7)<<4, double-buffered), B coalesced from L2.
__global__ __launch_bounds__(256) void k_gemm_mid(
    const short* __restrict__ xb, const short* __restrict__ agg,
    const short* __restrict__ prodD, const short* __restrict__ prodR,
    const short* __restrict__ BpVu, const short* __restrict__ BpEu,
    const float* __restrict__ P,
    short* __restrict__ uvb, short* __restrict__ tvb,
    short* __restrict__ teDb, short* __restrict__ teRb)
{
    __shared__ __align__(16) short lds[2][64 * 64];   // 16 KB
    int t = threadIdx.x, l = t & 63, w = t >> 6;
    int type = blockIdx.x >> 7, rs = blockIdx.x & 127;
    int r0 = rs << 6;

    const short* A0; const short* A1; int nchunk, ktbase;
    const bf16x8* Bp; short* Out;
    if (type == 0)      { A0 = xb;    A1 = agg;   nchunk = 16; Bp = (const bf16x8*)BpVu; ktbase = 0;  Out = uvb;  }
    else if (type == 1) { A0 = xb;    A1 = xb;    nchunk = 8;  Bp = (const bf16x8*)BpEu; ktbase = 0;  Out = tvb;  }
    else if (type == 2) { A0 = prodD; A1 = prodD; nchunk = 8;  Bp = (const bf16x8*)BpEu; ktbase = 16; Out = teDb; }
    else                { A0 = prodR; A1 = prodR; nchunk = 8;  Bp = (const bf16x8*)BpEu; ktbase = 16; Out = teRb; }

    // staging geometry: thread t writes 2x16B; dest rows dr, dr+32;
    // physical col bytes (t&7)*16 hold logical cols ((t&7)^(dr&7))*16
    int dr = t >> 3;
    int lcs = ((t & 7) ^ (dr & 7)) << 3;       // logical col offset in shorts
    int sr0 = (r0 + dr) << 9, sr1 = (r0 + dr + 32) << 9;

    f32x4 acc[4][4];
    #pragma unroll
    for (int mi = 0; mi < 4; ++mi)
        #pragma unroll
        for (int nf = 0; nf < 4; ++nf) acc[mi][nf] = (f32x4){0.f, 0.f, 0.f, 0.f};

    bf16x8 g0 = *(const bf16x8*)(A0 + sr0 + lcs);
    bf16x8 g1 = *(const bf16x8*)(A0 + sr1 + lcs);

    int buf = 0;
    for (int kc = 0; kc < nchunk; ++kc) {
        ((bf16x8*)lds[buf])[t] = g0;
        ((bf16x8*)lds[buf])[256 + t] = g1;
        __syncthreads();
        if (kc + 1 < nchunk) {
            int kn = kc + 1;
            const short* S = (kn < 8) ? A0 : A1;
            int off = (kn & 7) << 6;
            g0 = *(const bf16x8*)(S + sr0 + off + lcs);
            g1 = *(const bf16x8*)(S + sr1 + off + lcs);
        }
        const short* Lb = lds[buf];
        #pragma unroll
        for (int kt = 0; kt < 2; ++kt) {
            bf16x8 af[4];
            #pragma unroll
            for (int mi = 0; mi < 4; ++mi) {
                int row = (mi << 4) + (l & 15);
                int lcolb = (kt << 6) + ((l >> 4) << 4);
                int addr = (row << 6) + ((lcolb ^ ((row & 7) << 4)) >> 1);
                af[mi] = *(const bf16x8*)(Lb + addr);
            }
            int kt32 = ktbase + (kc << 1) + kt;
            #pragma unroll
            for (int nf = 0; nf < 4; ++nf) {
                bf16x8 b = Bp[((((w << 2) + nf) << 5) + kt32) * 64 + l];
                #pragma unroll
                for (int mi = 0; mi < 4; ++mi)
                    acc[mi][nf] = __builtin_amdgcn_mfma_f32_16x16x32_bf16(af[mi], b, acc[mi][nf], 0, 0, 0);
            }
        }
        buf ^= 1;
    }

    #pragma unroll
    for (int nf = 0; nf < 4; ++nf) {
        int col = (w << 6) + (nf << 4) + (l & 15);
        float aa = P[8 + col], cc = P[264 + col];
        #pragma unroll
        for (int mi = 0; mi < 4; ++mi) {
            int rbase = r0 + (mi << 4) + ((l >> 4) << 2);
            #pragma unroll
            for (int j = 0; j < 4; ++j) {
                float v = acc[mi][nf][j];
                if (type == 0) v = fmaxf(fmaf(v, aa, cc), 0.f);
                Out[(rbase + j) * 256 + col] = f2bf(v);
            }
        }
    }
}

// Elementwise combine with cyclic shifts (ue_U/ue_L are shifted TeD/TeR):
//   ue_U[r]=relu(a3*(Tv[r]+TeD[h-1])+c3), ue_D: TeD[r], ue_L: TeR[w-1], ue_R: TeR[r]
//   ur = relu(a4*(w0*ueU+w1*ueD+w2*ueL+w3*ueR)+c4); upd = uv*ur
__global__ __launch_bounds__(256) void k_ur_upd(
    const short* __restrict__ tv, const short* __restrict__ teD,
    const short* __restrict__ teR, const short* __restrict__ uv,
    const float* __restrict__ P, short* __restrict__ upd)
{
    int idx = blockIdx.x * 256 + threadIdx.x;   // 8192*32
    int n = idx >> 5, c8 = idx & 31;
    int bh = n >> 6, h = bh & 63, w = n & 63;
    int bhb = bh & ~63;
    int nUp = ((bhb + ((h + 63) & 63)) << 6) + w;
    int nLf = (bh << 6) + ((w + 63) & 63);

    const bf16x8* TV = (const bf16x8*)tv;
    const bf16x8* TD = (const bf16x8*)teD;
    const bf16x8* TR = (const bf16x8*)teR;
    const bf16x8* UV = (const bf16x8*)uv;
    bf16x8 vTv = TV[n * 32 + c8];
    bf16x8 vD  = TD[n * 32 + c8];
    bf16x8 vDu = TD[nUp * 32 + c8];
    bf16x8 vR  = TR[n * 32 + c8];
    bf16x8 vRl = TR[nLf * 32 + c8];
    bf16x8 vUv = UV[n * 32 + c8];

    float w0 = P[2060], w1 = P[2061], w2 = P[2062], w3 = P[2063];
    float a4 = P[2], c4 = P[3];
    f32x4 a3lo = *(const f32x4*)&P[520 + c8 * 8], a3hi = *(const f32x4*)&P[524 + c8 * 8];
    f32x4 c3lo = *(const f32x4*)&P[776 + c8 * 8], c3hi = *(const f32x4*)&P[780 + c8 * 8];

    bf16x8 o;
    #pragma unroll
    for (int j = 0; j < 8; ++j) {
        float a3 = (j < 4) ? a3lo[j & 3] : a3hi[j & 3];
        float c3 = (j < 4) ? c3lo[j & 3] : c3hi[j & 3];
        float tvv = bf2f(vTv[j]);
        float ueU = fmaxf(fmaf(a3, tvv + bf2f(vDu[j]), c3), 0.f);
        float ueD = fmaxf(fmaf(a3, tvv + bf2f(vD[j]),  c3), 0.f);
        float ueL = fmaxf(fmaf(a3, tvv + bf2f(vRl[j]), c3), 0.f);
        float ueR = fmaxf(fmaf(a3, tvv + bf2f(vR[j]),  c3), 0.f);
        float s = w0 * ueU + w1 * ueD + w2 * ueL + w3 * ueR;
        float ur = fmaxf(fmaf(a4, s, c4), 0.f);
        o[j] = f2bf(ur * bf2f(vUv[j]));
    }
    ((bf16x8*)upd)[n * 32 + c8] = o;
}

// out = relu(bn5([xb, upd] @ W_fc)) : [8192,768]@[768,512], f32 out
// block: 32 rows x 256 cols (col-half cg), 4 waves (wave = 32x64)
__global__ __launch_bounds__(256) void k_gemm_out(
    const short* __restrict__ xb, const short* __restrict__ upd,
    const short* __restrict__ BpFc, const float* __restrict__ P,
    float* __restrict__ out)
{
    __shared__ __align__(16) short lds[2][32 * 64];   // 8 KB
    int t = threadIdx.x, l = t & 63, w = t >> 6;
    int rs = blockIdx.x >> 1, cg = blockIdx.x & 1;
    int r0 = rs << 5;
    const bf16x8* Bp = (const bf16x8*)BpFc;

    int dr = t >> 3;
    int lcs = ((t & 7) ^ (dr & 7)) << 3;

    f32x4 acc[2][4];
    #pragma unroll
    for (int mi = 0; mi < 2; ++mi)
        #pragma unroll
        for (int nf = 0; nf < 4; ++nf) acc[mi][nf] = (f32x4){0.f, 0.f, 0.f, 0.f};

    bf16x8 g0 = *(const bf16x8*)(xb + ((r0 + dr) << 9) + lcs);
    int buf = 0;
    for (int kc = 0; kc < 12; ++kc) {
        ((bf16x8*)lds[buf])[t] = g0;
        __syncthreads();
        if (kc + 1 < 12) {
            int kn = kc + 1;
            if (kn < 8) g0 = *(const bf16x8*)(xb  + ((r0 + dr) << 9) + (kn << 6) + lcs);
            else        g0 = *(const bf16x8*)(upd + ((r0 + dr) << 8) + ((kn - 8) << 6) + lcs);
        }
        const short* Lb = lds[buf];
        #pragma unroll
        for (int kt = 0; kt < 2; ++kt) {
            bf16x8 af[2];
            #pragma unroll
            for (int mi = 0; mi < 2; ++mi) {
                int row = (mi << 4) + (l & 15);
                int lcolb = (kt << 6) + ((l >> 4) << 4);
                int addr = (row << 6) + ((lcolb ^ ((row & 7) << 4)) >> 1);
                af[mi] = *(const bf16x8*)(Lb + addr);
            }
            #pragma unroll
            for (int nf = 0; nf < 4; ++nf) {
                int nt = (cg << 4) + (w << 2) + nf;
                bf16x8 b = Bp[(nt * 24 + (kc << 1) + kt) * 64 + l];
                #pragma unroll
                for (int mi = 0; mi < 2; ++mi)
                    acc[mi][nf] = __builtin_amdgcn_mfma_f32_16x16x32_bf16(af[mi], b, acc[mi][nf], 0, 0, 0);
            }
        }
        buf ^= 1;
    }

    #pragma unroll
    for (int nf = 0; nf < 4; ++nf) {
        int col = (cg << 8) + (w << 6) + (nf << 4) + (l & 15);
        float a5 = P[1032 + col], c5 = P[1544 + col];
        #pragma unroll
        for (int mi = 0; mi < 2; ++mi) {
            int rbase = r0 + (mi << 4) + ((l >> 4) << 2);
            #pragma unroll
            for (int j = 0; j < 4; ++j) {
                out[(rbase + j) * 512 + col] = fmaxf(fmaf(acc[mi][nf][j], a5, c5), 0.f);
            }
        }
    }
}

extern "C" void kernel_launch(void* const* d_in, const int* in_sizes, int n_in,
                              void* d_out, int out_size, void* d_ws, size_t ws_size,
                              hipStream_t stream)
{
    const float* x    = (const float*)d_in[0];
    const float* w_ea = (const float*)d_in[1];
    const float* b_ea = (const float*)d_in[2];
    const float* g1   = (const float*)d_in[3];
    const float* b1   = (const float*)d_in[4];
    const float* m1   = (const float*)d_in[5];
    const float* v1   = (const float*)d_in[6];
    const float* w_vu = (const float*)d_in[7];
    const float* b_vu = (const float*)d_in[8];
    const float* g2   = (const float*)d_in[9];
    const float* b2   = (const float*)d_in[10];
    const float* m2   = (const float*)d_in[11];
    const float* v2   = (const float*)d_in[12];
    const float* w_eu = (const float*)d_in[13];
    const float* b_eu = (const float*)d_in[14];
    const float* g3   = (const float*)d_in[15];
    const float* b3   = (const float*)d_in[16];
    const float* m3   = (const float*)d_in[17];
    const float* v3   = (const float*)d_in[18];
    const float* w_er = (const float*)d_in[19];
    const float* b_er = (const float*)d_in[20];
    const float* g4   = (const float*)d_in[21];
    const float* b4   = (const float*)d_in[22];
    const float* m4   = (const float*)d_in[23];
    const float* v4   = (const float*)d_in[24];
    const float* w_fc = (const float*)d_in[25];
    const float* g5   = (const float*)d_in[26];
    const float* b5   = (const float*)d_in[27];
    const float* m5   = (const float*)d_in[28];
    const float* v5   = (const float*)d_in[29];

    char* ws = (char*)d_ws;
    float* P = (float*)ws;
    size_t off = 16384;
    short* BpVu = (short*)(ws + off); off += (size_t)1024 * 256 * 2;
    short* BpEu = (short*)(ws + off); off += (size_t)1024 * 256 * 2;
    short* BpFc = (short*)(ws + off); off += (size_t)768 * 512 * 2;
    short* xbb  = (short*)(ws + off); off += (size_t)8192 * 512 * 2;
    short* aggb = (short*)(ws + off); off += (size_t)8192 * 512 * 2;
    short* prodD = (short*)(ws + off); off += (size_t)8192 * 512 * 2;
    short* prodR = (short*)(ws + off); off += (size_t)8192 * 512 * 2;
    short* uvb  = (short*)(ws + off); off += (size_t)8192 * 256 * 2;
    short* tvb  = (short*)(ws + off); off += (size_t)8192 * 256 * 2;
    short* teDb = (short*)(ws + off); off += (size_t)8192 * 256 * 2;
    short* teRb = (short*)(ws + off); off += (size_t)8192 * 256 * 2;
    short* updb = (short*)(ws + off); off += (size_t)8192 * 256 * 2;

    k_setup<<<449, 256, 0, stream>>>(w_vu, w_eu, w_fc, BpVu, BpEu, BpFc,
                                     w_ea, b_ea, g1, b1, m1, v1,
                                     b_vu, g2, b2, m2, v2,
                                     b_eu, g3, b3, m3, v3,
                                     w_er, b_er, g4, b4, m4, v4,
                                     g5, b5, m5, v5, P);
    k_cvt_agg<<<2048, 256, 0, stream>>>(x, P, xbb, aggb, prodD, prodR);
    k_gemm_mid<<<512, 256, 0, stream>>>(xbb, aggb, prodD, prodR, BpVu, BpEu, P,
                                        uvb, tvb, teDb, teRb);
    k_ur_upd<<<1024, 256, 0, stream>>>(tvb, teDb, teRb, uvb, P, updb);
    k_gemm_out<<<512, 256, 0, stream>>>(xbb, updb, BpFc, P, (float*)d_out);
}

// Round 5
// 69.677 us; speedup vs baseline: 2.0922x; 1.0901x over previous
//
#include <hip/hip_runtime.h>
#include <stdint.h>

// ---------------------------------------------------------------------------
// GraphBasedSkipConnection, MI355X. f32 I/O; bf16 MFMA GEMMs internally.
//   B=2, H=64, W=64, C=512, C2=256, N = 8192 pixels.
// Round 5:
//  - 3 kernels: front (stencil+pack+params), gemm_mid (uv/Tv/TeD/TeR,
//    32-row blocks, grid 1024), gemm_out (upd computed in-kernel into LDS,
//    grid 1024). 4 blocks/CU for both GEMMs.
// ---------------------------------------------------------------------------

typedef __attribute__((ext_vector_type(8))) short bf16x8;
typedef __attribute__((ext_vector_type(4))) float f32x4;

#define EPS_BN 1e-3f

__device__ __forceinline__ short f2bf(float f) {
    union { float f; unsigned u; } cv;
    cv.f = f;
    unsigned r = cv.u + 0x7fffu + ((cv.u >> 16) & 1u);
    return (short)(r >> 16);
}
__device__ __forceinline__ float bf2f(short s) {
    union { unsigned u; float f; } cv;
    cv.u = ((unsigned)(unsigned short)s) << 16;
    return cv.f;
}

// ---- P layout (floats) -----------------------------------------------------
// 0 a1, 1 c1, 2 a4, 3 c4
// 8..264    a2[256]     264..520  c2[256]
// 520..776  a3[256]     776..1032 c3[256]
// 1032..1544 a5[512]    1544..2056 c5[512]
// 2056..2060 w_ea[4]    2060..2064 w_er[4]
// ---------------------------------------------------------------------------

// Pack W[K, Ncol] (row-major f32) into bf16 MFMA B-fragment order:
// tile = nt*(K/32)+kt ; packed[(tile*64+lane)*8+j] = W[kt*32+(lane>>4)*8+j][nt*16+(lane&15)]
__device__ __forceinline__ void pack_one(const float* __restrict__ W, short* __restrict__ out,
                                         int K, int Ncol, int lb, int tid) {
    int i = lb * 256 + tid;
    int lane = i & 63, tile = i >> 6;
    int ktiles = K >> 5;
    int nt = tile / ktiles, kt = tile - nt * ktiles;
    int kbase = (kt << 5) + ((lane >> 4) << 3);
    int col = (nt << 4) + (lane & 15);
    bf16x8 v;
    #pragma unroll
    for (int j = 0; j < 8; ++j) v[j] = f2bf(W[(kbase + j) * Ncol + col]);
    ((bf16x8*)out)[(tile << 6) + lane] = v;
}

// blocks 0..2047: stencil; 2048..2175 pack W_vu; 2176..2303 pack W_eu;
// 2304..2495 pack W_fc; 2496 computes P.
__global__ __launch_bounds__(256) void k_front(
    const float* __restrict__ x,
    const float* w_ea, const float* b_ea,
    const float* g1, const float* b1, const float* m1, const float* v1,
    const float* w_vu, const float* w_eu, const float* w_fc,
    const float* b_vu, const float* g2, const float* b2_, const float* m2, const float* v2,
    const float* b_eu, const float* g3, const float* b3, const float* m3, const float* v3,
    const float* w_er, const float* b_er,
    const float* g4, const float* b4, const float* m4, const float* v4,
    const float* g5, const float* b5, const float* m5, const float* v5,
    short* __restrict__ xb, short* __restrict__ agg,
    short* __restrict__ prodD, short* __restrict__ prodR,
    short* BpVu, short* BpEu, short* BpFc, float* P)
{
    int blk = blockIdx.x, t = threadIdx.x;
    if (blk >= 2048) {
        int b = blk - 2048;
        if (b < 128)      { pack_one(w_vu, BpVu, 1024, 256, b, t); }
        else if (b < 256) { pack_one(w_eu, BpEu, 1024, 256, b - 128, t); }
        else if (b < 448) { pack_one(w_fc, BpFc,  768, 512, b - 256, t); }
        else {
            for (int u = t; u < 512; u += 256) {
                float a5 = g5[u] * rsqrtf(v5[u] + EPS_BN);
                P[1032 + u] = a5;
                P[1544 + u] = b5[u] - m5[u] * a5;      // w_fc has no bias
            }
            {
                float a2 = g2[t] * rsqrtf(v2[t] + EPS_BN);
                P[8 + t]   = a2;
                P[264 + t] = (b_vu[t] - m2[t]) * a2 + b2_[t];
                float a3 = g3[t] * rsqrtf(v3[t] + EPS_BN);
                P[520 + t] = a3;
                P[776 + t] = (b_eu[t] - m3[t]) * a3 + b3[t];
            }
            if (t < 4) {
                P[2056 + t] = w_ea[t];
                P[2060 + t] = w_er[t];
            }
            if (t == 0) {
                float a4 = g4[0] * rsqrtf(v4[0] + EPS_BN);
                P[2] = a4;
                P[3] = (b_er[0] - m4[0]) * a4 + b4[0];
                float a1l = g1[0] * rsqrtf(v1[0] + EPS_BN);
                P[0] = a1l;
                P[1] = (b_ea[0] - m1[0]) * a1l + b1[0];
            }
        }
        return;
    }

    // stencil part: computes its own a1/c1/w_ea (no dependency on P)
    float a1 = g1[0] * rsqrtf(v1[0] + EPS_BN);
    float c1 = (b_ea[0] - m1[0]) * a1 + b1[0];
    float w0 = w_ea[0], w1 = w_ea[1], w2 = w_ea[2], w3 = w_ea[3];

    int idx = blk * 256 + t;                    // N*C/8 threads
    int n = idx >> 6;
    int ci = idx & 63;
    int bh = n >> 6, h = bh & 63, w = n & 63;
    int bhb = bh & ~63;
    int rowU = ((bhb + ((h + 63) & 63)) << 6) + w;
    int rowD = ((bhb + ((h + 1) & 63)) << 6) + w;
    int rowL = (bh << 6) + ((w + 63) & 63);
    int rowR = (bh << 6) + ((w + 1) & 63);

    const f32x4* xv = (const f32x4*)x;
    int c4 = ci << 1;
    f32x4 vc[2], vU[2], vD[2], vL[2], vR[2];
    #pragma unroll
    for (int h2 = 0; h2 < 2; ++h2) {
        vc[h2] = xv[(n    << 7) + c4 + h2];
        vU[h2] = xv[(rowU << 7) + c4 + h2];
        vD[h2] = xv[(rowD << 7) + c4 + h2];
        vL[h2] = xv[(rowL << 7) + c4 + h2];
        vR[h2] = xv[(rowR << 7) + c4 + h2];
    }

    bf16x8 ob, xbv, pD, pR;
    #pragma unroll
    for (int h2 = 0; h2 < 2; ++h2) {
        #pragma unroll
        for (int j = 0; j < 4; ++j) {
            int e = h2 * 4 + j;
            float xc = vc[h2][j];
            float eU = xc * vU[h2][j], eD = xc * vD[h2][j];
            float eL = xc * vL[h2][j], eR = xc * vR[h2][j];
            float S = w0 * eU + w1 * eD + w2 * eL + w3 * eR;
            ob[e]  = f2bf(fmaxf(fmaf(a1, S, c1), 0.f));
            xbv[e] = f2bf(xc);
            pD[e] = f2bf(eD); pR[e] = f2bf(eR);
        }
    }
    int o = (n << 6) + ci;
    ((bf16x8*)agg)[o] = ob;
    ((bf16x8*)xb)[o] = xbv;
    ((bf16x8*)prodD)[o] = pD;
    ((bf16x8*)prodR)[o] = pR;
}

// Unified middle GEMMs, type = blockIdx&3 (interleaved for balance):
//   type 0: uv  = relu(bn2([xb,agg] @ W_vu))    K=1024
//   type 1: Tv  = xb    @ Weu_top               K=512  (raw bf16)
//   type 2: TeD = prodD @ Weu_bot               K=512  (raw bf16)
//   type 3: TeR = prodR @ Weu_bot               K=512  (raw bf16)
// block: 32 rows x 256 cols, 4 waves (wave = 32x64), grid 1024 (4 blk/CU).
__global__ __launch_bounds__(256) void k_gemm_mid(
    const short* __restrict__ xb, const short* __restrict__ agg,
    const short* __restrict__ prodD, const short* __restrict__ prodR,
    const short* __restrict__ BpVu, const short* __restrict__ BpEu,
    const float* __restrict__ P,
    short* __restrict__ uvb, short* __restrict__ tvb,
    short* __restrict__ teDb, short* __restrict__ teRb)
{
    __shared__ __align__(16) short sA[2][32 * 64];    // 8 KB
    int t = threadIdx.x, l = t & 63, w = t >> 6;
    int type = blockIdx.x & 3, rs = blockIdx.x >> 2;
    int r0 = rs << 5;

    const short* A0; const short* A1; int nchunk, ktbase;
    const bf16x8* Bp; short* Out;
    if (type == 0)      { A0 = xb;    A1 = agg;   nchunk = 16; Bp = (const bf16x8*)BpVu; ktbase = 0;  Out = uvb;  }
    else if (type == 1) { A0 = xb;    A1 = xb;    nchunk = 8;  Bp = (const bf16x8*)BpEu; ktbase = 0;  Out = tvb;  }
    else if (type == 2) { A0 = prodD; A1 = prodD; nchunk = 8;  Bp = (const bf16x8*)BpEu; ktbase = 16; Out = teDb; }
    else                { A0 = prodR; A1 = prodR; nchunk = 8;  Bp = (const bf16x8*)BpEu; ktbase = 16; Out = teRb; }

    int dr = t >> 3;
    int lcs = ((t & 7) ^ (dr & 7)) << 3;       // swizzled logical col offset (shorts)
    int srow = (r0 + dr) << 9;

    f32x4 acc[2][4];
    #pragma unroll
    for (int mi = 0; mi < 2; ++mi)
        #pragma unroll
        for (int nf = 0; nf < 4; ++nf) acc[mi][nf] = (f32x4){0.f, 0.f, 0.f, 0.f};

    bf16x8 g0 = *(const bf16x8*)(A0 + srow + lcs);

    int buf = 0;
    for (int kc = 0; kc < nchunk; ++kc) {
        ((bf16x8*)sA[buf])[t] = g0;
        __syncthreads();
        if (kc + 1 < nchunk) {
            int kn = kc + 1;
            const short* S = (kn < 8) ? A0 : A1;
            g0 = *(const bf16x8*)(S + srow + ((kn & 7) << 6) + lcs);
        }
        const short* Lb = sA[buf];
        #pragma unroll
        for (int kt = 0; kt < 2; ++kt) {
            bf16x8 af[2];
            #pragma unroll
            for (int mi = 0; mi < 2; ++mi) {
                int row = (mi << 4) + (l & 15);
                int lcolb = (kt << 6) + ((l >> 4) << 4);
                int addr = (row << 6) + ((lcolb ^ ((row & 7) << 4)) >> 1);
                af[mi] = *(const bf16x8*)(Lb + addr);
            }
            int kt32 = ktbase + (kc << 1) + kt;
            #pragma unroll
            for (int nf = 0; nf < 4; ++nf) {
                bf16x8 b = Bp[((((w << 2) + nf) << 5) + kt32) * 64 + l];
                #pragma unroll
                for (int mi = 0; mi < 2; ++mi)
                    acc[mi][nf] = __builtin_amdgcn_mfma_f32_16x16x32_bf16(af[mi], b, acc[mi][nf], 0, 0, 0);
            }
        }
        buf ^= 1;
    }

    #pragma unroll
    for (int nf = 0; nf < 4; ++nf) {
        int col = (w << 6) + (nf << 4) + (l & 15);
        float aa = P[8 + col], cc = P[264 + col];
        #pragma unroll
        for (int mi = 0; mi < 2; ++mi) {
            int rbase = r0 + (mi << 4) + ((l >> 4) << 2);
            #pragma unroll
            for (int j = 0; j < 4; ++j) {
                float v = acc[mi][nf][j];
                if (type == 0) v = fmaxf(fmaf(v, aa, cc), 0.f);
                Out[(rbase + j) * 256 + col] = f2bf(v);
            }
        }
    }
}

// out = relu(bn5([xb, upd] @ W_fc)), upd computed in-kernel into LDS:
//   ue_U=relu(a3*(Tv+TeD[h-1])+c3), ue_D: TeD, ue_L: TeR[w-1], ue_R: TeR
//   ur = relu(a4*(w0*ueU+w1*ueD+w2*ueL+w3*ueR)+c4); upd = uv*ur
// block: 32 rows x 128 cols (col quarter cq), 4 waves (wave = 32x32),
// grid = 256 rowsets x 4 = 1024 blocks.
__global__ __launch_bounds__(256) void k_gemm_out(
    const short* __restrict__ xb,
    const short* __restrict__ tv, const short* __restrict__ teD,
    const short* __restrict__ teR, const short* __restrict__ uv,
    const short* __restrict__ BpFc, const float* __restrict__ P,
    float* __restrict__ out)
{
    __shared__ __align__(16) short sA[2][32 * 64];    // 8 KB (xb chunks)
    __shared__ __align__(16) short updL[4][32 * 64];  // 16 KB (upd, swizzled)
    int t = threadIdx.x, l = t & 63, w = t >> 6;
    int cq = blockIdx.x & 3, rs = blockIdx.x >> 2;
    int r0 = rs << 5;
    const bf16x8* Bp = (const bf16x8*)BpFc;

    int dr = t >> 3;                            // local row 0..31
    int p8 = t & 7;                             // physical 8-short group
    int lcs = (p8 ^ (dr & 7)) << 3;             // swizzled logical col (shorts)

    // ---- prologue: compute upd for rows r0..r0+31, all 256 channels ----
    {
        int n = r0 + dr;
        int bh = n >> 6, h = bh & 63, ww = n & 63;
        int bhb = bh & ~63;
        int nUp = ((bhb + ((h + 63) & 63)) << 6) + ww;
        int nLf = (bh << 6) + ((ww + 63) & 63);
        float w0 = P[2060], w1 = P[2061], w2 = P[2062], w3 = P[2063];
        float a4 = P[2], c4 = P[3];
        #pragma unroll
        for (int q = 0; q < 4; ++q) {
            int lc = (q << 6) + lcs;            // logical channel base
            bf16x8 vTv = *(const bf16x8*)(tv  + n   * 256 + lc);
            bf16x8 vD  = *(const bf16x8*)(teD + n   * 256 + lc);
            bf16x8 vDu = *(const bf16x8*)(teD + nUp * 256 + lc);
            bf16x8 vR  = *(const bf16x8*)(teR + n   * 256 + lc);
            bf16x8 vRl = *(const bf16x8*)(teR + nLf * 256 + lc);
            bf16x8 vUv = *(const bf16x8*)(uv  + n   * 256 + lc);
            f32x4 a3a = *(const f32x4*)&P[520 + lc], a3b = *(const f32x4*)&P[524 + lc];
            f32x4 c3a = *(const f32x4*)&P[776 + lc], c3b = *(const f32x4*)&P[780 + lc];
            bf16x8 o;
            #pragma unroll
            for (int j = 0; j < 8; ++j) {
                float a3 = (j < 4) ? a3a[j & 3] : a3b[j & 3];
                float c3 = (j < 4) ? c3a[j & 3] : c3b[j & 3];
                float tvv = bf2f(vTv[j]);
                float ueU = fmaxf(fmaf(a3, tvv + bf2f(vDu[j]), c3), 0.f);
                float ueD = fmaxf(fmaf(a3, tvv + bf2f(vD[j]),  c3), 0.f);
                float ueL = fmaxf(fmaf(a3, tvv + bf2f(vRl[j]), c3), 0.f);
                float ueR = fmaxf(fmaf(a3, tvv + bf2f(vR[j]),  c3), 0.f);
                float s = w0 * ueU + w1 * ueD + w2 * ueL + w3 * ueR;
                float ur = fmaxf(fmaf(a4, s, c4), 0.f);
                o[j] = f2bf(ur * bf2f(vUv[j]));
            }
            *(bf16x8*)&updL[q][(dr << 6) + (p8 << 3)] = o;   // swizzled store
        }
    }

    f32x4 acc[2][2];
    #pragma unroll
    for (int mi = 0; mi < 2; ++mi)
        #pragma unroll
        for (int nf = 0; nf < 2; ++nf) acc[mi][nf] = (f32x4){0.f, 0.f, 0.f, 0.f};

    bf16x8 g0 = *(const bf16x8*)(xb + ((r0 + dr) << 9) + lcs);
    int buf = 0;
    for (int kc = 0; kc < 12; ++kc) {
        const short* Lb;
        if (kc < 8) {
            ((bf16x8*)sA[buf])[t] = g0;
            __syncthreads();
            if (kc + 1 < 8)
                g0 = *(const bf16x8*)(xb + ((r0 + dr) << 9) + ((kc + 1) << 6) + lcs);
            Lb = sA[buf];
            buf ^= 1;
        } else {
            Lb = updL[kc - 8];
        }
        #pragma unroll
        for (int kt = 0; kt < 2; ++kt) {
            bf16x8 af[2];
            #pragma unroll
            for (int mi = 0; mi < 2; ++mi) {
                int row = (mi << 4) + (l & 15);
                int lcolb = (kt << 6) + ((l >> 4) << 4);
                int addr = (row << 6) + ((lcolb ^ ((row & 7) << 4)) >> 1);
                af[mi] = *(const bf16x8*)(Lb + addr);
            }
            #pragma unroll
            for (int nf = 0; nf < 2; ++nf) {
                int nt = (cq << 3) + (w << 1) + nf;
                bf16x8 b = Bp[(nt * 24 + (kc << 1) + kt) * 64 + l];
                #pragma unroll
                for (int mi = 0; mi < 2; ++mi)
                    acc[mi][nf] = __builtin_amdgcn_mfma_f32_16x16x32_bf16(af[mi], b, acc[mi][nf], 0, 0, 0);
            }
        }
    }

    #pragma unroll
    for (int nf = 0; nf < 2; ++nf) {
        int col = (cq << 7) + (w << 5) + (nf << 4) + (l & 15);
        float a5 = P[1032 + col], c5 = P[1544 + col];
        #pragma unroll
        for (int mi = 0; mi < 2; ++mi) {
            int rbase = r0 + (mi << 4) + ((l >> 4) << 2);
            #pragma unroll
            for (int j = 0; j < 4; ++j) {
                out[(rbase + j) * 512 + col] = fmaxf(fmaf(acc[mi][nf][j], a5, c5), 0.f);
            }
        }
    }
}

extern "C" void kernel_launch(void* const* d_in, const int* in_sizes, int n_in,
                              void* d_out, int out_size, void* d_ws, size_t ws_size,
                              hipStream_t stream)
{
    const float* x    = (const float*)d_in[0];
    const float* w_ea = (const float*)d_in[1];
    const float* b_ea = (const float*)d_in[2];
    const float* g1   = (const float*)d_in[3];
    const float* b1   = (const float*)d_in[4];
    const float* m1   = (const float*)d_in[5];
    const float* v1   = (const float*)d_in[6];
    const float* w_vu = (const float*)d_in[7];
    const float* b_vu = (const float*)d_in[8];
    const float* g2   = (const float*)d_in[9];
    const float* b2   = (const float*)d_in[10];
    const float* m2   = (const float*)d_in[11];
    const float* v2   = (const float*)d_in[12];
    const float* w_eu = (const float*)d_in[13];
    const float* b_eu = (const float*)d_in[14];
    const float* g3   = (const float*)d_in[15];
    const float* b3   = (const float*)d_in[16];
    const float* m3   = (const float*)d_in[17];
    const float* v3   = (const float*)d_in[18];
    const float* w_er = (const float*)d_in[19];
    const float* b_er = (const float*)d_in[20];
    const float* g4   = (const float*)d_in[21];
    const float* b4   = (const float*)d_in[22];
    const float* m4   = (const float*)d_in[23];
    const float* v4   = (const float*)d_in[24];
    const float* w_fc = (const float*)d_in[25];
    const float* g5   = (const float*)d_in[26];
    const float* b5   = (const float*)d_in[27];
    const float* m5   = (const float*)d_in[28];
    const float* v5   = (const float*)d_in[29];

    char* ws = (char*)d_ws;
    float* P = (float*)ws;
    size_t off = 16384;
    short* BpVu = (short*)(ws + off); off += (size_t)1024 * 256 * 2;
    short* BpEu = (short*)(ws + off); off += (size_t)1024 * 256 * 2;
    short* BpFc = (short*)(ws + off); off += (size_t)768 * 512 * 2;
    short* xbb  = (short*)(ws + off); off += (size_t)8192 * 512 * 2;
    short* aggb = (short*)(ws + off); off += (size_t)8192 * 512 * 2;
    short* prodD = (short*)(ws + off); off += (size_t)8192 * 512 * 2;
    short* prodR = (short*)(ws + off); off += (size_t)8192 * 512 * 2;
    short* uvb  = (short*)(ws + off); off += (size_t)8192 * 256 * 2;
    short* tvb  = (short*)(ws + off); off += (size_t)8192 * 256 * 2;
    short* teDb = (short*)(ws + off); off += (size_t)8192 * 256 * 2;
    short* teRb = (short*)(ws + off); off += (size_t)8192 * 256 * 2;

    k_front<<<2497, 256, 0, stream>>>(x, w_ea, b_ea, g1, b1, m1, v1,
                                      w_vu, w_eu, w_fc,
                                      b_vu, g2, b2, m2, v2,
                                      b_eu, g3, b3, m3, v3,
                                      w_er, b_er, g4, b4, m4, v4,
                                      g5, b5, m5, v5,
                                      xbb, aggb, prodD, prodR,
                                      BpVu, BpEu, BpFc, P);
    k_gemm_mid<<<1024, 256, 0, stream>>>(xbb, aggb, prodD, prodR, BpVu, BpEu, P,
                                         uvb, tvb, teDb, teRb);
    k_gemm_out<<<1024, 256, 0, stream>>>(xbb, tvb, teDb, teRb, uvb, BpFc, P,
                                         (float*)d_out);
}